// Round 4
// baseline (91.073 us; speedup 1.0000x reference)
//
#include <hip/hip_runtime.h>
#include <cstdint>
#include <cstddef>

#define NROWS 100000
#define FIN 512
#define HIDDEN 256
#define NCLS 50

typedef __attribute__((ext_vector_type(8))) short s16x8;
typedef __attribute__((ext_vector_type(4))) float f32x4;
typedef __attribute__((ext_vector_type(16))) float f32x16;

// scalar fp32->bf16 RNE
__device__ __forceinline__ unsigned short f2bf(float f) {
  unsigned int u = __float_as_uint(f);
  u += 0x7fffu + ((u >> 16) & 1u);
  return (unsigned short)(u >> 16);
}

// packed fp32x2 -> bf16x2 (RNE), single VALU op
__device__ __forceinline__ unsigned int cvt_pk_bf16(float lo, float hi) {
  unsigned int r;
  asm("v_cvt_pk_bf16_f32 %0, %1, %2" : "=v"(r) : "v"(lo), "v"(hi));
  return r;
}

__device__ __forceinline__ void gload_lds16(const void* g, void* l) {
  __builtin_amdgcn_global_load_lds(
      (const __attribute__((address_space(1))) void*)g,
      (__attribute__((address_space(3))) void*)l, 16, 0, 0);
}

__device__ __forceinline__ f32x16 mfma32(s16x8 a, s16x8 b, f32x16 c) {
  return __builtin_amdgcn_mfma_f32_32x32x16_bf16(a, b, c, 0, 0, 0);
}

// prep: w1t[n][k] = bf16(W1[k][n])  [256][512]   (blocks 0..31, LDS transpose)
//       w2t[c][k] = bf16(W2[k][c]), c>=50 -> 0   [64][256]   (blocks 32..35)
__global__ __launch_bounds__(256) void prep_kernel(
    const float* __restrict__ W1, const float* __restrict__ W2,
    unsigned short* __restrict__ w1t, unsigned short* __restrict__ w2t) {
  __shared__ float tile[64][65];
  const int b = blockIdx.x, t = threadIdx.x;
  if (b < 32) {
    const int k0 = (b >> 2) * 64, n0 = (b & 3) * 64;
    const int rq = t >> 6, col = t & 63;
#pragma unroll
    for (int i = 0; i < 16; ++i) {
      int row = i * 4 + rq;
      tile[row][col] = W1[(size_t)(k0 + row) * HIDDEN + n0 + col];
    }
    __syncthreads();
#pragma unroll
    for (int i = 0; i < 16; ++i) {
      int n = i * 4 + rq;
      w1t[(size_t)(n0 + n) * FIN + k0 + col] = f2bf(tile[col][n]);
    }
  } else {
    const int b2i = b - 32;
#pragma unroll
    for (int i = 0; i < 16; ++i) {
      int idx = t + i * 256;
      int c = idx >> 6;
      int k = b2i * 64 + (idx & 63);
      float v = (c < NCLS) ? W2[(size_t)k * NCLS + c] : 0.0f;
      w2t[(size_t)c * HIDDEN + k] = f2bf(v);
    }
  }
}

// Fused MLP + log_softmax. 512 thr / 8 waves. Tile 128x256, BK=32, 32x32x16 MFMA.
// Wave grid 2M x 4N (wave tile 64x64; acc = 2x2 f32x16).
// LDS map (64KB):
//   K-loop : A dbuf [0,16K) 2x8KB bf16 frag-ordered; B dbuf [16K,48K) 2x16KB
//   epilog : h-half [0,32K) frag-ordered; w2t [32K,64K); LSE exch [0,1K) (after h dead)
__global__ __launch_bounds__(512, 4) void fused_kernel(
    const float* __restrict__ x, const unsigned short* __restrict__ w1t,
    const unsigned short* __restrict__ w2t, const float* __restrict__ b1,
    const float* __restrict__ b2, float* __restrict__ out) {
  __shared__ char smem[65536];

  const int t = threadIdx.x;
  const int lane = t & 63, wid = t >> 6;
  const int l31 = lane & 31, l5 = lane >> 5;
  const int wrM = wid >> 2, wcN = wid & 3;
  const int bm = blockIdx.x;

  // ---- A staging role: thread -> (row = t>>2, chunk s = t&3 of 8 fp32) ----
  const int arow = t >> 2, as4 = t & 3;
  int growA = bm * 128 + arow;
  if (growA > NROWS - 1) growA = NROWS - 1;
  const float* const asrc = x + (size_t)growA * FIN + as4 * 8;
  // frag-ordered dest: [wg][ksub][mf][slot] x16B, slot = (s&1)*32 + row&31
  char* const aw_dst0 = smem + (arow >> 6) * 4096 + (as4 >> 1) * 2048 +
                        ((arow >> 5) & 1) * 1024 +
                        ((((as4 & 1) << 5) + (arow & 31)) << 4);

  // ---- B staging role: [col][4 slots of 8 bf16], slot s holds global chunk
  //      s ^ f(col), f(col) = ((col>>1)&1)<<1 ----
  const unsigned short* bsrc[2];
  char* bdst[2];
#pragma unroll
  for (int i = 0; i < 2; ++i) {
    const int c = t + i * 512;
    const int colB = c >> 2, sB = c & 3;
    const int sg = sB ^ (((colB >> 1) & 1) << 1);
    bsrc[i] = w1t + (size_t)colB * FIN + sg * 8;
    bdst[i] = smem + 16384 + c * 16;
  }
  auto stage_B = [&](int buf, int k0) {
#pragma unroll
    for (int i = 0; i < 2; ++i) gload_lds16(bsrc[i] + k0, bdst[i] + buf * 16384);
  };

  // loop-invariant frag read offsets (bytes)
  int aro[2][2], bro[2][2];  // [ksub][mfi] / [ksub][nfi]
#pragma unroll
  for (int ksub = 0; ksub < 2; ++ksub) {
#pragma unroll
    for (int mfi = 0; mfi < 2; ++mfi)
      aro[ksub][mfi] = wrM * 4096 + ksub * 2048 + mfi * 1024 + lane * 16;
#pragma unroll
    for (int nfi = 0; nfi < 2; ++nfi) {
      const int colR = wcN * 64 + nfi * 32 + l31;
      const int slotR = ((ksub << 1) + l5) ^ (((l31 >> 1) & 1) << 1);
      bro[ksub][nfi] = 16384 + colR * 64 + slotR * 16;
    }
  }

  f32x16 acc[2][2];
#pragma unroll
  for (int i = 0; i < 2; ++i)
#pragma unroll
    for (int j = 0; j < 2; ++j)
#pragma unroll
      for (int r = 0; r < 16; ++r) acc[i][j][r] = 0.0f;

  // prologue: A(0), B(0)
  {
    float4 a0 = ((const float4*)asrc)[0];
    float4 a1 = ((const float4*)asrc)[1];
    stage_B(0, 0);
    unsigned int u0 = cvt_pk_bf16(a0.x, a0.y), u1 = cvt_pk_bf16(a0.z, a0.w);
    unsigned int u2 = cvt_pk_bf16(a1.x, a1.y), u3 = cvt_pk_bf16(a1.z, a1.w);
    *(uint4*)aw_dst0 = make_uint4(u0, u1, u2, u3);
  }
  __syncthreads();

  for (int ks = 0; ks < 16; ++ks) {
    const int cur = ks & 1;
    float4 na0, na1;
    if (ks < 15) {
      na0 = ((const float4*)(asrc + (ks + 1) * 32))[0];
      na1 = ((const float4*)(asrc + (ks + 1) * 32))[1];
      stage_B(cur ^ 1, (ks + 1) * 32);
    }
    const int ab = cur * 8192, bb = cur * 16384;
    s16x8 af[2][2], bfv[2][2];
#pragma unroll
    for (int ksub = 0; ksub < 2; ++ksub) {
#pragma unroll
      for (int mfi = 0; mfi < 2; ++mfi)
        af[ksub][mfi] = *(const s16x8*)(smem + ab + aro[ksub][mfi]);
#pragma unroll
      for (int nfi = 0; nfi < 2; ++nfi)
        bfv[ksub][nfi] = *(const s16x8*)(smem + bb + bro[ksub][nfi]);
    }
#pragma unroll
    for (int ksub = 0; ksub < 2; ++ksub)
#pragma unroll
      for (int mfi = 0; mfi < 2; ++mfi)
#pragma unroll
        for (int nfi = 0; nfi < 2; ++nfi)
          acc[mfi][nfi] = mfma32(af[ksub][mfi], bfv[ksub][nfi], acc[mfi][nfi]);
    if (ks < 15) {
      unsigned int u0 = cvt_pk_bf16(na0.x, na0.y), u1 = cvt_pk_bf16(na0.z, na0.w);
      unsigned int u2 = cvt_pk_bf16(na1.x, na1.y), u3 = cvt_pk_bf16(na1.z, na1.w);
      *(uint4*)(aw_dst0 + (cur ^ 1) * 8192) = make_uint4(u0, u1, u2, u3);
    }
    __syncthreads();
  }

  // ================= epilogue =================
  // stage w2t -> [32K,64K): [class][32 chunks], slot s holds chunk s^(row&7)
#pragma unroll
  for (int i = 0; i < 4; ++i) {
    const int c = t + i * 512;
    const int rw = c >> 5, sl = c & 31;
    gload_lds16(w2t + (size_t)rw * 256 + (sl ^ (rw & 7)) * 8, smem + 32768 + c * 16);
  }

  // h-write: frag-ordered [rg][ksub][slot]: slot = (k8&1)*32 + (crow ^ (k8&3))
  auto write_h = [&]() {
    float b1c[2];
#pragma unroll
    for (int nfi = 0; nfi < 2; ++nfi) b1c[nfi] = b1[wcN * 64 + nfi * 32 + l31];
#pragma unroll
    for (int nfi = 0; nfi < 2; ++nfi) {
      const int col = wcN * 64 + nfi * 32 + l31;
      const int cbase = ((col >> 4) << 10) + (((col >> 3) & 1) << 9) + ((col & 7) << 1);
      const int x2 = (col >> 3) & 3;
#pragma unroll
      for (int mfi = 0; mfi < 2; ++mfi) {
        char* const hb = smem + mfi * 16384 + cbase;
#pragma unroll
        for (int r = 0; r < 16; ++r) {
          const int crow = (r & 3) + ((r >> 2) << 3) + (l5 << 2);
          float v = fmaxf(acc[mfi][nfi][r] + b1c[nfi], 0.0f);
          *(unsigned short*)(hb + ((crow ^ x2) << 4)) = (unsigned short)cvt_pk_bf16(v, v);
        }
      }
    }
  };

  const int local = wid & 3;
  const int rg = local & 1, cgw = local >> 1;
  const int classc = cgw * 32 + l31;
  const bool valid = classc < NCLS;
  const float bias2v = valid ? b2[classc] : 0.0f;
  f32x16 acc2;
#pragma unroll
  for (int r = 0; r < 16; ++r) acc2[r] = 0.0f;

  auto gemm2_kloop = [&]() {
#pragma unroll
    for (int ksub = 0; ksub < 16; ++ksub) {
      const int k8a = (ksub << 1) + l5;
      s16x8 a2 = *(const s16x8*)(smem + rg * 16384 + (ksub << 10) +
                                 ((lane ^ (k8a & 3)) << 4));
      s16x8 b2f = *(const s16x8*)(smem + 32768 + classc * 512 +
                                  ((k8a ^ (classc & 7)) << 4));
      acc2 = mfma32(a2, b2f, acc2);
    }
  };

  auto lse_partial = [&]() {
#pragma unroll
    for (int r = 0; r < 16; ++r) {
      const int crow = (r & 3) + ((r >> 2) << 3) + (l5 << 2);
      float v = valid ? (acc2[r] + bias2v) : -3.0e38f;
      float m = v;
#pragma unroll
      for (int off = 16; off >= 1; off >>= 1) m = fmaxf(m, __shfl_xor(m, off, 64));
      float sE = valid ? __expf(v - m) : 0.0f;
#pragma unroll
      for (int off = 16; off >= 1; off >>= 1) sE += __shfl_xor(sE, off, 64);
      if (l31 == 0)
        *(float2*)(smem + cgw * 512 + (rg * 32 + crow) * 8) = make_float2(m, sE);
    }
  };

  auto lse_store = [&](int p) {
#pragma unroll
    for (int r = 0; r < 16; ++r) {
      const int crow = (r & 3) + ((r >> 2) << 3) + (l5 << 2);
      const int rowid = rg * 32 + crow;
      float2 e0 = *(const float2*)(smem + cgw * 512 + rowid * 8);
      float2 e1 = *(const float2*)(smem + (cgw ^ 1) * 512 + rowid * 8);
      float M = fmaxf(e0.x, e1.x);
      float lz = __logf(e0.y * __expf(e0.x - M) + e1.y * __expf(e1.x - M));
      const int grow = bm * 128 + p * 64 + rowid;
      if (valid && grow < NROWS)
        out[(size_t)grow * NCLS + classc] = acc2[r] + bias2v - M - lz;
    }
  };

  // pass 0: rows 0..63 (owners: waves wrM==0)
  if (wrM == 0) write_h();
  __syncthreads();                    // h0 + w2t DMA complete
  if (wrM == 0) gemm2_kloop();
  __syncthreads();                    // all pass-0 h reads done (h0 dead)
  if (wrM == 0) lse_partial();
  __syncthreads();
  if (wrM == 0) lse_store(0);
  __syncthreads();                    // LSE region reads done before h1 overwrite
  // pass 1: rows 64..127 (owners: waves wrM==1)
  if (wrM == 1) write_h();
  __syncthreads();
  if (wrM == 1) gemm2_kloop();
  __syncthreads();
  if (wrM == 1) lse_partial();
  __syncthreads();
  if (wrM == 1) lse_store(1);
}

extern "C" void kernel_launch(void* const* d_in, const int* in_sizes, int n_in,
                              void* d_out, int out_size, void* d_ws, size_t ws_size,
                              hipStream_t stream) {
  const float* x  = (const float*)d_in[0];
  // d_in[1] = edge_index: dead (ALPHA==1.0 makes APPNP the identity)
  const float* W1 = (const float*)d_in[2];
  const float* b1 = (const float*)d_in[3];
  const float* W2 = (const float*)d_in[4];
  const float* b2 = (const float*)d_in[5];
  float* out = (float*)d_out;

  char* ws = (char*)d_ws;
  unsigned short* w1t = (unsigned short*)(ws);           // 256 KB
  unsigned short* w2t = (unsigned short*)(ws + 262144);  // 32 KB

  prep_kernel<<<36, 256, 0, stream>>>(W1, W2, w1t, w2t);
  fused_kernel<<<(NROWS + 127) / 128, 512, 0, stream>>>(x, w1t, w2t, b1, b2, out);
}

// Round 5
// 69.275 us; speedup vs baseline: 1.3147x; 1.3147x over previous
//
#include <hip/hip_runtime.h>
#include <cstdint>
#include <cstddef>

#define NROWS 100000
#define FIN 512
#define HIDDEN 256
#define NCLS 50

typedef __attribute__((ext_vector_type(8))) short s16x8;
typedef __attribute__((ext_vector_type(4))) float f32x4;

// round-to-nearest-even fp32->bf16 (scalar)
__device__ __forceinline__ unsigned short f2bf(float f) {
  unsigned int u = __float_as_uint(f);
  u += 0x7fffu + ((u >> 16) & 1u);
  return (unsigned short)(u >> 16);
}

// packed fp32x2 -> bf16x2 (RNE) - single VALU op
__device__ __forceinline__ unsigned int cvt_pk_bf16(float lo, float hi) {
  unsigned int r;
  asm("v_cvt_pk_bf16_f32 %0, %1, %2" : "=v"(r) : "v"(lo), "v"(hi));
  return r;
}

__device__ __forceinline__ void gload_lds16(const void* g, void* l) {
  __builtin_amdgcn_global_load_lds(
      (const __attribute__((address_space(1))) void*)g,
      (__attribute__((address_space(3))) void*)l, 16, 0, 0);
}

__device__ __forceinline__ f32x4 mfma_bf16(s16x8 a, s16x8 b, f32x4 c) {
  return __builtin_amdgcn_mfma_f32_16x16x32_bf16(a, b, c, 0, 0, 0);
}

// prep: w1t[n][k] = bf16(W1[k][n])  [256][512]   (blocks 0..31, LDS transpose)
//       w2t[c][k] = bf16(W2[k][c]), c>=50 -> 0   [64][256]   (blocks 32..35)
__global__ __launch_bounds__(256) void prep_kernel(
    const float* __restrict__ W1, const float* __restrict__ W2,
    unsigned short* __restrict__ w1t, unsigned short* __restrict__ w2t) {
  __shared__ float tile[64][65];
  const int b = blockIdx.x, t = threadIdx.x;
  if (b < 32) {
    const int k0 = (b >> 2) * 64, n0 = (b & 3) * 64;
    const int rq = t >> 6, col = t & 63;
#pragma unroll
    for (int i = 0; i < 16; ++i) {
      int row = i * 4 + rq;
      tile[row][col] = W1[(size_t)(k0 + row) * HIDDEN + n0 + col];
    }
    __syncthreads();
#pragma unroll
    for (int i = 0; i < 16; ++i) {
      int n = i * 4 + rq;
      w1t[(size_t)(n0 + n) * FIN + k0 + col] = f2bf(tile[col][n]);
    }
  } else {
    const int b2i = b - 32;  // 0..3, k-range
#pragma unroll
    for (int i = 0; i < 16; ++i) {
      int idx = t + i * 256;          // 0..4095
      int c = idx >> 6;               // 0..63
      int k = b2i * 64 + (idx & 63);  // 0..255
      float v = (c < NCLS) ? W2[(size_t)k * NCLS + c] : 0.0f;
      w2t[(size_t)c * HIDDEN + k] = f2bf(v);
    }
  }
}

// Fused: out = log_softmax(relu(x@W1+b1) @ W2 + b2)
// 512 threads / 8 waves (4M x 2N), tile 128 rows x 256 cols, BK=32.
// A: fp32 via global_load_lds (pre-swizzled source, linear dest), dbuf 2x16KB.
// B: w1t bf16 via global_load_lds, dbuf 2x16KB.  Total LDS 64KB -> 2 blocks/CU.
// K-loop uses COUNTED vmcnt (4 loads/thread stay in flight across the barrier,
// never drained to 0 in-loop) + raw s_barrier, instead of __syncthreads()'s
// vmcnt(0) full drain. (T3/T4 counted-vmcnt pattern.)
// Epilogue: two-pass GEMM2 (h-half 32KB in A-region, w2t 32KB in B-region).
__global__ __launch_bounds__(512, 4) void fused_kernel(
    const float* __restrict__ x, const unsigned short* __restrict__ w1t,
    const unsigned short* __restrict__ w2t, const float* __restrict__ b1,
    const float* __restrict__ b2, float* __restrict__ out) {
  __shared__ char smem[65536];
  float* const Abase = (float*)smem;                              // 2 x 16KB fp32
  unsigned short* const Bbase = (unsigned short*)(smem + 32768);  // 2 x 16KB bf16

  const int t = threadIdx.x;
  const int lane = t & 63, wid = t >> 6;
  const int q = lane & 15, half = lane >> 4;
  const int wr = wid >> 1, wc = wid & 1;
  const int bm = blockIdx.x;

  // ---- staging: A tile [128 rows][32 f32] = 1024 chunks(16B), 2/thread ----
  // lds chunk (row,s) holds global chunk s^(row&7)  (128B-window permute)
  auto stage_A = [&](float* buf, int k0) {
#pragma unroll
    for (int i = 0; i < 2; ++i) {
      int c = t + i * 512;
      int row = c >> 3, s = c & 7;
      int grow = bm * 128 + row;
      if (grow > NROWS - 1) grow = NROWS - 1;
      gload_lds16(x + (size_t)grow * FIN + k0 + ((s ^ (row & 7)) << 2),
                  buf + c * 4);
    }
  };
  // ---- B tile [256 cols][32 bf16] = 1024 chunks, 2/thread ----
  // lds chunk (col,s) holds global chunk s^((col>>2)&3)  (64B-window permute)
  auto stage_B = [&](unsigned short* buf, int k0) {
#pragma unroll
    for (int i = 0; i < 2; ++i) {
      int c = t + i * 512;
      int col = c >> 2, s = c & 3;
      gload_lds16(w1t + (size_t)col * FIN + k0 + ((s ^ ((col >> 2) & 3)) << 3),
                  buf + c * 8);
    }
  };

  f32x4 acc[2][8];
  const f32x4 z4 = {0.f, 0.f, 0.f, 0.f};
#pragma unroll
  for (int m = 0; m < 2; ++m)
#pragma unroll
    for (int n = 0; n < 8; ++n) acc[m][n] = z4;

  // compute step: read fragments from buf `cur`, do 16 MFMAs
  auto kstep_compute = [&](int cur) {
    float* Ac = Abase + cur * 4096;
    unsigned short* Bc = Bbase + cur * 8192;
    s16x8 af[2];
#pragma unroll
    for (int m = 0; m < 2; ++m) {
      const int row = wr * 32 + m * 16 + q;
      const int cb = row * 8;
      f32x4 lo = *(const f32x4*)(Ac + (cb + ((half * 2) ^ (q & 7))) * 4);
      f32x4 hi = *(const f32x4*)(Ac + (cb + ((half * 2 + 1) ^ (q & 7))) * 4);
      union { unsigned int u[4]; s16x8 v; } cvu;
      cvu.u[0] = cvt_pk_bf16(lo[0], lo[1]);
      cvu.u[1] = cvt_pk_bf16(lo[2], lo[3]);
      cvu.u[2] = cvt_pk_bf16(hi[0], hi[1]);
      cvu.u[3] = cvt_pk_bf16(hi[2], hi[3]);
      af[m] = cvu.v;
    }
#pragma unroll
    for (int n = 0; n < 8; ++n) {
      const int col = wc * 128 + n * 16 + q;
      s16x8 bf = *(const s16x8*)(Bc + col * 32 + ((half ^ ((q >> 2) & 3)) << 3));
      acc[0][n] = mfma_bf16(af[0], bf, acc[0][n]);
      acc[1][n] = mfma_bf16(af[1], bf, acc[1][n]);
    }
  };

  // prologue: stage step 0, full drain once
  stage_A(Abase, 0);
  stage_B(Bbase, 0);
  asm volatile("s_waitcnt vmcnt(0)" ::: "memory");
  __builtin_amdgcn_s_barrier();
  __builtin_amdgcn_sched_barrier(0);

  for (int ks = 0; ks < 15; ++ks) {
    const int cur = ks & 1;
    // issue next step's 4 loads (2 A + 2 B) -> they stay in flight past barrier
    stage_A(Abase + (cur ^ 1) * 4096, (ks + 1) * 32);
    stage_B(Bbase + (cur ^ 1) * 8192, (ks + 1) * 32);
    // wait only for OLDER loads (this step's data); newest 4 remain outstanding
    asm volatile("s_waitcnt vmcnt(4)" ::: "memory");
    __builtin_amdgcn_s_barrier();        // all waves' step-ks data in LDS
    __builtin_amdgcn_sched_barrier(0);   // pin ds_reads below the barrier
    kstep_compute(cur);
    __builtin_amdgcn_s_barrier();        // all reads of buf `cur` done
    __builtin_amdgcn_sched_barrier(0);   // (next iter DMA overwrites buf cur)
  }
  // last step (ks = 15, cur = 1): nothing left to stage -> drain all
  asm volatile("s_waitcnt vmcnt(0)" ::: "memory");
  __builtin_amdgcn_s_barrier();
  __builtin_amdgcn_sched_barrier(0);
  kstep_compute(1);
  __syncthreads();  // all B-buf reads done before epilogue DMA reuses region

  // ================= epilogue =================
  unsigned short* const hls = (unsigned short*)smem;   // [64][256] bf16, 32KB
  unsigned short* const wls = Bbase;                   // [64][256] bf16, 32KB
  const int p_of_wave = wid >> 2;  // waves 0-3 own rows 0-63, 4-7 own 64-127

  // stage w2t once (all threads): lds chunk (row,s) holds global chunk s^(row&7)
#pragma unroll
  for (int i = 0; i < 4; ++i) {
    int c = t + i * 512;
    int row = c >> 5, s = c & 31;
    gload_lds16(w2t + (size_t)row * HIDDEN + ((s ^ (row & 7)) << 3), wls + c * 8);
  }

  // h-write lambda: local row rl in 0..63, swizzle ch = (col>>3)^(rl&7)
  auto write_h = [&]() {
#pragma unroll
    for (int n = 0; n < 8; ++n) {
      const int col = wc * 128 + n * 16 + q;
      const float bias = b1[col];
      const int chs = col & 7;
#pragma unroll
      for (int m = 0; m < 2; ++m) {
        const int rl0 = (wr & 1) * 32 + m * 16 + half * 4;
#pragma unroll
        for (int r = 0; r < 4; ++r) {
          const int rl = rl0 + r;
          float v = fmaxf(acc[m][n][r] + bias, 0.0f);
          const int ch = (col >> 3) ^ (rl & 7);
          hls[rl * 256 + ch * 8 + chs] = f2bf(v);
        }
      }
    }
  };

  // GEMM2 pass over 64 rows by 4 waves (aw = wid&3): 16 rows x 64 cols each
  auto gemm2_pass = [&](int p) {
    f32x4 acc2[4];
#pragma unroll
    for (int n = 0; n < 4; ++n) acc2[n] = z4;
    const int arl = (wid & 3) * 16 + q;
#pragma unroll
    for (int ks = 0; ks < HIDDEN; ks += 32) {
      const int g = (ks >> 3) + half;
      s16x8 a2 = *(const s16x8*)(hls + arl * 256 + ((g ^ (arl & 7)) << 3));
#pragma unroll
      for (int n = 0; n < 4; ++n) {
        const int c = n * 16 + q;
        s16x8 b2f = *(const s16x8*)(wls + c * 256 + ((g ^ (c & 7)) << 3));
        acc2[n] = mfma_bf16(a2, b2f, acc2[n]);
      }
    }
    float bias2[4];
#pragma unroll
    for (int n = 0; n < 4; ++n) {
      const int c = n * 16 + q;
      bias2[n] = (c < NCLS) ? b2[c] : 0.0f;
    }
#pragma unroll
    for (int r = 0; r < 4; ++r) {
      float vals[4];
      float mx = -1e30f;
#pragma unroll
      for (int n = 0; n < 4; ++n) {
        const int c = n * 16 + q;
        float v = acc2[n][r] + bias2[n];
        vals[n] = v;
        if (c < NCLS) mx = fmaxf(mx, v);
      }
      for (int off = 8; off >= 1; off >>= 1)
        mx = fmaxf(mx, __shfl_xor(mx, off, 64));
      float s = 0.f;
#pragma unroll
      for (int n = 0; n < 4; ++n) {
        const int c = n * 16 + q;
        if (c < NCLS) s += __expf(vals[n] - mx);
      }
      for (int off = 8; off >= 1; off >>= 1) s += __shfl_xor(s, off, 64);
      const float lz = __logf(s);
      const int rowg = bm * 128 + p * 64 + (wid & 3) * 16 + half * 4 + r;
      if (rowg < NROWS) {
#pragma unroll
        for (int n = 0; n < 4; ++n) {
          const int c = n * 16 + q;
          if (c < NCLS) out[(size_t)rowg * NCLS + c] = vals[n] - mx - lz;
        }
      }
    }
  };

  if (p_of_wave == 0) write_h();   // h rows 0..63
  __syncthreads();                 // drains w2t glds + h writes
  if (p_of_wave == 0) gemm2_pass(0);
  __syncthreads();                 // pass-0 reads done
  if (p_of_wave == 1) write_h();   // h rows 64..127 overwrite hls
  __syncthreads();
  if (p_of_wave == 1) gemm2_pass(1);
}

extern "C" void kernel_launch(void* const* d_in, const int* in_sizes, int n_in,
                              void* d_out, int out_size, void* d_ws, size_t ws_size,
                              hipStream_t stream) {
  const float* x  = (const float*)d_in[0];
  // d_in[1] = edge_index: dead (ALPHA==1.0 makes APPNP the identity)
  const float* W1 = (const float*)d_in[2];
  const float* b1 = (const float*)d_in[3];
  const float* W2 = (const float*)d_in[4];
  const float* b2 = (const float*)d_in[5];
  float* out = (float*)d_out;

  char* ws = (char*)d_ws;
  unsigned short* w1t = (unsigned short*)(ws);           // 256 KB
  unsigned short* w2t = (unsigned short*)(ws + 262144);  // 32 KB

  prep_kernel<<<36, 256, 0, stream>>>(W1, W2, w1t, w2t);
  fused_kernel<<<(NROWS + 127) / 128, 512, 0, stream>>>(x, w1t, w2t, b1, b2, out);
}